// Round 17
// baseline (66.959 us; speedup 1.0000x reference)
//
#include <hip/hip_runtime.h>
#include <math.h>

// Tropical max/min-plus pseudo-matmul.
// out[b,u] = max_f(x[b,f] + w[f,u]) for u<128, min_f otherwise.
//
// R28 = R26 VERBATIM (best measured: 66.88, passed, absmax 0).
// R27 post-mortem: halving the fence count via s_load_dwordx8 2-step
// frames FAILED correctness (absmax 3.125) -- the f32x8 frames introduce
// compiler-materialized sub-register extracts between load-issue and the
// lgkmcnt(0) fence; any extract scheduled before the data returns captures
// garbage (rule #18's failure mode, with an intermediate the SB(0) pair
// doesn't provably pin). Per pre-commit: revert to R26 and lock in.
// Final ledger:
//   Confirmed: v_pk_add_f32 op_sel broadcast (-1.34), w dist-2 (-0.42),
//     x s_load x2->x4 (-0.36), SMEM x + TLP=4 (-0.3).
//   Falsified: x-path (LDS/VMEM/SMEM tie), 2 blocks/CU (x2, one clean),
//     phase-lock, w-depth on VGPR-tight base, deeper SMEM frames (R27).
//   Floors: VALU 1.0 inst/cell (4 pk_add + 4 max3 / 8 cells; no
//     v_pk_max_f32 on CDNA); fence cadence at the OOO-SMEM lgkmcnt(0)-only
//     + 102-SGPR architectural limit.
// Kernel ~9.5us vs 5.1us packed-VALU roofline; dur_us residual is fixed
// harness overhead (2x ~41us fills + gaps), not kernel-addressable.

#define FEAT  512
#define UNITS 256
#define BR    8            // rows per block
#define NW    16           // waves per block (8 k-slices x 2 halves)
#define KW    64           // k per wave
#define NS    (KW / 4)     // 16 steps, 4 k per step
#define LDSZ  24576        // 96KB declared (occupancy belt); 64KB used

typedef float f32x2 __attribute__((ext_vector_type(2)));
typedef float f32x4 __attribute__((ext_vector_type(4)));

__device__ __forceinline__ float max3f(float a, float b, float c) {
    return fmaxf(fmaxf(a, b), c);   // v_max3_f32
}
__device__ __forceinline__ float min3f(float a, float b, float c) {
    return fminf(fminf(a, b), c);   // v_min3_f32
}

// one s_load_dwordx4 at compile-time byte offset (template -> guaranteed imm)
template<int OFF>
__device__ __forceinline__ void sload4(const float* __restrict__ p, f32x4& d) {
    asm volatile("s_load_dwordx4 %0, %1, %2" : "=s"(d) : "s"(p), "i"(OFF));
}

// 8 s_load_dwordx4: x[row0+r][k0..k0+3] as one SGPR quad/row (offsets r*2048);
// halves split into the f32x2 pk_add operand layout (sub-register copies).
__device__ __forceinline__ void sload_xstep(const float* __restrict__ xp_s,
                                            f32x2* __restrict__ xb) {
    f32x4 q[BR];
    sload4<0 * 2048>(xp_s, q[0]);
    sload4<1 * 2048>(xp_s, q[1]);
    sload4<2 * 2048>(xp_s, q[2]);
    sload4<3 * 2048>(xp_s, q[3]);
    sload4<4 * 2048>(xp_s, q[4]);
    sload4<5 * 2048>(xp_s, q[5]);
    sload4<6 * 2048>(xp_s, q[6]);
    sload4<7 * 2048>(xp_s, q[7]);
    #pragma unroll
    for (int r = 0; r < BR; ++r) {
        xb[2 * r]     = (f32x2){q[r].x, q[r].y};
        xb[2 * r + 1] = (f32x2){q[r].z, q[r].w};
    }
}

__device__ __forceinline__ void smem_wait_fenced() {
    __builtin_amdgcn_sched_barrier(0);                 // pin cover-compute above
    asm volatile("s_waitcnt lgkmcnt(0)" ::: "memory"); // SMEM is OOO: only 0 valid
    __builtin_amdgcn_sched_barrier(0);                 // pin consumers below
}

// packed add, src0 = SGPR pair, lo half broadcast to both result lanes
__device__ __forceinline__ f32x2 pk_add_lo(f32x2 xs, f32x2 wv) {
    f32x2 d;
    asm("v_pk_add_f32 %0, %1, %2 op_sel:[0,0] op_sel_hi:[0,1]"
        : "=v"(d) : "s"(xs), "v"(wv));
    return d;
}
// packed add, hi half of the SGPR pair broadcast to both result lanes
__device__ __forceinline__ f32x2 pk_add_hi(f32x2 xs, f32x2 wv) {
    f32x2 d;
    asm("v_pk_add_f32 %0, %1, %2 op_sel:[1,0] op_sel_hi:[1,1]"
        : "=v"(d) : "s"(xs), "v"(wv));
    return d;
}

// 4 dwordx2: w[k0+j][u0..u0+1] -- 64 lanes x 8B = 512B contiguous
__device__ __forceinline__ void load_wstep(const float* __restrict__ wp, int s,
                                           f32x2* __restrict__ wb) {
    #pragma unroll
    for (int j = 0; j < 4; ++j)
        wb[j] = *(const f32x2*)(wp + (size_t)(s * 4 + j) * UNITS);
}

// per step: 8 rows x (4 pk_add + 4 max3/min3) = 64 VALU inst
template<bool ISMAX>
__device__ __forceinline__ void compute_step(const f32x2* __restrict__ xb,
                                             const f32x2* __restrict__ wq,
                                             f32x2* __restrict__ acc) {
    #pragma unroll
    for (int r = 0; r < BR; ++r) {
        const f32x2 t0 = pk_add_lo(xb[2 * r],     wq[0]);  // x[4s]   + w-row 4s
        const f32x2 t1 = pk_add_hi(xb[2 * r],     wq[1]);  // x[4s+1] + w-row 4s+1
        const f32x2 t2 = pk_add_lo(xb[2 * r + 1], wq[2]);  // x[4s+2] + w-row 4s+2
        const f32x2 t3 = pk_add_hi(xb[2 * r + 1], wq[3]);  // x[4s+3] + w-row 4s+3
        f32x2 A = acc[r];
        if (ISMAX) {
            A.x = max3f(A.x, t0.x, t1.x);  A.x = max3f(A.x, t2.x, t3.x);
            A.y = max3f(A.y, t0.y, t1.y);  A.y = max3f(A.y, t2.y, t3.y);
        } else {
            A.x = min3f(A.x, t0.x, t1.x);  A.x = min3f(A.x, t2.x, t3.x);
            A.y = min3f(A.y, t0.y, t1.y);  A.y = min3f(A.y, t2.y, t3.y);
        }
        acc[r] = A;
    }
}

// pipeline: x (SMEM) one step ahead, fence cadence == R23; w TWO steps
// ahead via named quad-buffer, steady-state x4 body, last iter peeled.
template<bool ISMAX>
__device__ __forceinline__ void main_loop(const float* __restrict__ xp,
                                          const float* __restrict__ wp,
                                          f32x2* __restrict__ acc) {
    f32x2 xA[BR * 2], xB[BR * 2];
    f32x2 W0[4], W1[4], W2[4], W3[4];
    sload_xstep(xp, xA);
    load_wstep(wp, 0, W0);
    load_wstep(wp, 1, W1);                    // 2 w-batches in flight
    smem_wait_fenced();                       // x batch 0 ready
    #pragma unroll 1
    for (int s = 0; s < NS - 4; s += 4) {     // s = 0,4,8 (steps 0..11)
        sload_xstep(xp + (s + 1) * 4, xB);
        load_wstep(wp, s + 2, W2);            // dist-2
        compute_step<ISMAX>(xA, W0, acc);
        smem_wait_fenced();

        sload_xstep(xp + (s + 2) * 4, xA);
        load_wstep(wp, s + 3, W3);
        compute_step<ISMAX>(xB, W1, acc);
        smem_wait_fenced();

        sload_xstep(xp + (s + 3) * 4, xB);
        load_wstep(wp, s + 4, W0);
        compute_step<ISMAX>(xA, W2, acc);
        smem_wait_fenced();

        sload_xstep(xp + (s + 4) * 4, xA);
        load_wstep(wp, s + 5, W1);
        compute_step<ISMAX>(xB, W3, acc);
        smem_wait_fenced();
    }
    // peeled tail: steps 12..15; xA=x(12), W0=w(12), W1=w(13) already live
    sload_xstep(xp + 13 * 4, xB);
    load_wstep(wp, 14, W2);
    compute_step<ISMAX>(xA, W0, acc);
    smem_wait_fenced();

    sload_xstep(xp + 14 * 4, xA);
    load_wstep(wp, 15, W3);
    compute_step<ISMAX>(xB, W1, acc);
    smem_wait_fenced();

    sload_xstep(xp + 15 * 4, xB);
    compute_step<ISMAX>(xA, W2, acc);
    smem_wait_fenced();

    compute_step<ISMAX>(xB, W3, acc);
}

__global__ __launch_bounds__(1024)
__attribute__((amdgpu_waves_per_eu(4, 4)))
void tropical_kernel(const float* __restrict__ x,
                     const float* __restrict__ w,
                     float* __restrict__ out) {
    __shared__ float lds[LDSZ];   // 96KB declared (belt); 64KB used
    const int tid  = threadIdx.x;
    const int lane = tid & 63;
    const int wv   = __builtin_amdgcn_readfirstlane(tid >> 6);  // 0..15
    const int kslice = wv & 7;           // k origin index
    const int half   = wv >> 3;          // 0: max units 0-127, 1: min 128-255
    const int ks   = kslice * KW;
    const int u0   = lane * 2;           // 2 units per lane, contiguous
    const int row0 = blockIdx.x * BR;

    const float* xp = x + (size_t)row0 * FEAT + ks;          // uniform
    const float* wp = w + (size_t)ks * UNITS + half * 128 + u0;

    f32x2 acc[BR];
    const float init = half ? __builtin_inff() : -__builtin_inff();
    #pragma unroll
    for (int r = 0; r < BR; ++r)
        acc[r] = (f32x2){init, init};

    if (half == 0) main_loop<true >(xp, wp, acc);
    else           main_loop<false>(xp, wp, acc);

    // ---- partials to LDS: wave wv -> slot wv, 128 units of its half ----
    #pragma unroll
    for (int r = 0; r < BR; ++r)
        *(f32x2*)&lds[(wv * BR + r) * 128 + u0] = acc[r];   // 512B/wave-row
    __syncthreads();   // the kernel's only barrier

    // ---- combine 8 k-slice partials; thread -> float2 of output ----
    const int r  = tid >> 7;             // 0..7
    const int j2 = tid & 127;
    const int hh = j2 >> 6;              // wave-uniform: 0=max half, 1=min half
    const int uo = (j2 & 63) * 2;        // unit offset within the half
    f32x2 v = *(const f32x2*)&lds[((hh * 8 + 0) * BR + r) * 128 + uo];
    #pragma unroll
    for (int j = 1; j < 8; ++j) {
        const f32x2 p = *(const f32x2*)&lds[((hh * 8 + j) * BR + r) * 128 + uo];
        if (hh == 0) { v.x = fmaxf(v.x, p.x); v.y = fmaxf(v.y, p.y); }
        else         { v.x = fminf(v.x, p.x); v.y = fminf(v.y, p.y); }
    }
    *(f32x2*)&out[(size_t)(row0 + r) * UNITS + hh * 128 + uo] = v;
}

extern "C" void kernel_launch(void* const* d_in, const int* in_sizes, int n_in,
                              void* d_out, int out_size, void* d_ws, size_t ws_size,
                              hipStream_t stream) {
    const float* x = (const float*)d_in[0];   // (2048, 512)
    const float* w = (const float*)d_in[1];   // (512, 256)
    float* out = (float*)d_out;               // (2048, 256)

    // 256 blocks x 16 waves = 1 block/CU, 4 waves/SIMD (R23/R25 geometry)
    tropical_kernel<<<dim3(2048 / BR), dim3(1024), 0, stream>>>(x, w, out);
}